// Round 10
// baseline (431.936 us; speedup 1.0000x reference)
//
#include <hip/hip_runtime.h>

typedef __bf16 bf16x8 __attribute__((ext_vector_type(8)));
typedef float f32x4 __attribute__((ext_vector_type(4)));
typedef unsigned short ushort_t;
typedef unsigned char uchar_t;

#define MFMA_16x16x32(A, B, C) __builtin_amdgcn_mfma_f32_16x16x32_bf16(A, B, C, 0, 0, 0)

__device__ __forceinline__ float bf2f(ushort_t u) {
  unsigned int x = ((unsigned int)u) << 16;
  float f;
  __builtin_memcpy(&f, &x, 4);
  return f;
}
__device__ __forceinline__ ushort_t f2bf(float f) {
  unsigned int x;
  __builtin_memcpy(&x, &f, 4);
  x = x + 0x7fffu + ((x >> 16) & 1u);
  return (ushort_t)(x >> 16);
}
__device__ __forceinline__ ushort_t f2bf_s(float f) {
  if (!(__builtin_fabsf(f) < 3.0e38f)) f = 0.0f;
  return f2bf(f);
}

__device__ __forceinline__ void gload_lds16(const void* g, void* l) {
  __builtin_amdgcn_global_load_lds(
      (__attribute__((address_space(1))) void*)const_cast<void*>(g),
      (__attribute__((address_space(3))) void*)l, 16, 0, 0);
}

__device__ __forceinline__ uint4 cvt8(float4 a, float4 b) {
  uint4 r;
  r.x = (unsigned)f2bf_s(a.x) | ((unsigned)f2bf_s(a.y) << 16);
  r.y = (unsigned)f2bf_s(a.z) | ((unsigned)f2bf_s(a.w) << 16);
  r.z = (unsigned)f2bf_s(b.x) | ((unsigned)f2bf_s(b.y) << 16);
  r.w = (unsigned)f2bf_s(b.z) | ((unsigned)f2bf_s(b.w) << 16);
  return r;
}

// XOR-granule swizzle (granule = 8 bf16 = 16B) for [R][1024] bf16 buffer.
__device__ __forceinline__ int sci32(int r, int col) {
  int g = col >> 3;
  g = (g & ~7) | ((g ^ r) & 7);
  return (r << 10) + (g << 3) + (col & 7);
}

// ---------------------------------------------------------------------------
// f32 -> bf16 bulk convert (sanitizing), 4 elems/thread
// ---------------------------------------------------------------------------
__launch_bounds__(256)
__global__ void cvt_f32_bf16(const float* __restrict__ in, ushort_t* __restrict__ out, int n4) {
  int i = blockIdx.x * 256 + threadIdx.x;
  if (i >= n4) return;
  float4 v = ((const float4*)in)[i];
  ushort4 r;
  r.x = f2bf_s(v.x);
  r.y = f2bf_s(v.y);
  r.z = f2bf_s(v.z);
  r.w = f2bf_s(v.w);
  ((ushort4*)out)[i] = r;
}

// ---------------------------------------------------------------------------
// bf16 BT-GEMM (m97 structure, global_load_lds w16). C[m,n]=sum_k A[m,k]B[n,k]
// SCATTER=false: C row-major bf16. SCATTER=true: Vt [B*H][64][1024] epilogue.
// ---------------------------------------------------------------------------
template <bool SCATTER>
__launch_bounds__(256)
__global__ void gemm_bt(const ushort_t* __restrict__ A, const ushort_t* __restrict__ B,
                        ushort_t* __restrict__ C) {
  constexpr int BK = 32, LD = 1024, K = 1024;
  constexpr int WM = 64, WN = 64, MR = 4, NR = 4;

  __shared__ ushort_t lA[128 * BK];
  __shared__ ushort_t lB[128 * BK];

  const int m0 = blockIdx.y * 128;
  const int n0 = blockIdx.x * 128;
  const int tid = threadIdx.x;
  const int lane = tid & 63, wid = tid >> 6;
  const int wr = wid >> 1, wc = wid & 1;

  f32x4 acc[MR][NR] = {};

  for (int k0 = 0; k0 < K; k0 += BK) {
#pragma unroll
    for (int i = 0; i < 2; ++i) {
      int idx = i * 256 + tid;
      const ushort_t* g = A + (long long)(m0 + (idx >> 2)) * LD + k0 + (idx & 3) * 8;
      gload_lds16(g, (void*)(lA + (i * 256 + wid * 64) * 8));
    }
#pragma unroll
    for (int i = 0; i < 2; ++i) {
      int idx = i * 256 + tid;
      const ushort_t* g = B + (long long)(n0 + (idx >> 2)) * LD + k0 + (idx & 3) * 8;
      gload_lds16(g, (void*)(lB + (i * 256 + wid * 64) * 8));
    }
    __syncthreads();

    bf16x8 af[MR], bf[NR];
#pragma unroll
    for (int m = 0; m < MR; ++m)
      af[m] = *(const bf16x8*)&lA[(wr * WM + m * 16 + (lane & 15)) * BK + (lane >> 4) * 8];
#pragma unroll
    for (int n = 0; n < NR; ++n)
      bf[n] = *(const bf16x8*)&lB[(wc * WN + n * 16 + (lane & 15)) * BK + (lane >> 4) * 8];
#pragma unroll
    for (int m = 0; m < MR; ++m)
#pragma unroll
      for (int n = 0; n < NR; ++n)
        acc[m][n] = MFMA_16x16x32(af[m], bf[n], acc[m][n]);
    __syncthreads();
  }

  if constexpr (!SCATTER) {
#pragma unroll
    for (int m = 0; m < MR; ++m)
#pragma unroll
      for (int n = 0; n < NR; ++n)
#pragma unroll
        for (int j = 0; j < 4; ++j) {
          int row = m0 + wr * WM + m * 16 + (lane >> 4) * 4 + j;
          int col = n0 + wc * WN + n * 16 + (lane & 15);
          C[(long long)row * LD + col] = f2bf(acc[m][n][j]);
        }
  } else {
#pragma unroll
    for (int m = 0; m < MR; ++m)
#pragma unroll
      for (int n = 0; n < NR; ++n) {
        int row = m0 + wr * WM + m * 16 + (lane >> 4) * 4;
        int col = n0 + wc * WN + n * 16 + (lane & 15);
        int b = row >> 10, s = row & 1023;
        int h = col >> 6, dk = col & 63;
        ushort4 pk;
        pk.x = f2bf(acc[m][n][0]);
        pk.y = f2bf(acc[m][n][1]);
        pk.z = f2bf(acc[m][n][2]);
        pk.w = f2bf(acc[m][n][3]);
        *(ushort4*)(C + ((long long)(b * 16 + h)) * 65536 + (long long)dk * 1024 + s) = pk;
      }
  }
}

// ---------------------------------------------------------------------------
// f32-input projection GEMM (fallback tiers) — validated round 4.
// ---------------------------------------------------------------------------
__launch_bounds__(256)
__global__ void gemm_proj(const float* __restrict__ A, const float* __restrict__ B,
                          ushort_t* __restrict__ C, int K, int lda, int ldb, int ldc) {
  constexpr int BM = 128, BN = 128, BK = 32;
  constexpr int WM = 64, WN = 64, MR = 4, NR = 4;
  __shared__ ushort_t lA[BM * BK];
  __shared__ ushort_t lB[BN * BK];
  const int m0 = blockIdx.y * BM, n0 = blockIdx.x * BN;
  const int tid = threadIdx.x, lane = tid & 63, wid = tid >> 6;
  const int wr = wid >> 1, wc = wid & 1;
  f32x4 acc[MR][NR] = {};
  for (int k0 = 0; k0 < K; k0 += BK) {
#pragma unroll
    for (int i = 0; i < 2; ++i) {
      int idx = i * 256 + tid;
      const float* g = A + (long long)(m0 + (idx >> 2)) * lda + k0 + (idx & 3) * 8;
      *(uint4*)&lA[idx * 8] = cvt8(*(const float4*)g, *(const float4*)(g + 4));
    }
#pragma unroll
    for (int i = 0; i < 2; ++i) {
      int idx = i * 256 + tid;
      const float* g = B + (long long)(n0 + (idx >> 2)) * ldb + k0 + (idx & 3) * 8;
      *(uint4*)&lB[idx * 8] = cvt8(*(const float4*)g, *(const float4*)(g + 4));
    }
    __syncthreads();
    bf16x8 af[MR], bf[NR];
#pragma unroll
    for (int m = 0; m < MR; ++m)
      af[m] = *(const bf16x8*)&lA[(wr * WM + m * 16 + (lane & 15)) * BK + (lane >> 4) * 8];
#pragma unroll
    for (int n = 0; n < NR; ++n)
      bf[n] = *(const bf16x8*)&lB[(wc * WN + n * 16 + (lane & 15)) * BK + (lane >> 4) * 8];
#pragma unroll
    for (int m = 0; m < MR; ++m)
#pragma unroll
      for (int n = 0; n < NR; ++n)
        acc[m][n] = MFMA_16x16x32(af[m], bf[n], acc[m][n]);
    __syncthreads();
  }
#pragma unroll
  for (int m = 0; m < MR; ++m)
#pragma unroll
    for (int n = 0; n < NR; ++n)
#pragma unroll
      for (int j = 0; j < 4; ++j) {
        int row = m0 + wr * WM + m * 16 + (lane >> 4) * 4 + j;
        int col = n0 + wc * WN + n * 16 + (lane & 15);
        C[(long long)row * ldc + col] = f2bf(acc[m][n][j]);
      }
}

// f32-input V projection with transpose-scatter epilogue — validated round 4.
__launch_bounds__(256)
__global__ void gemm_vt(const float* __restrict__ A, const float* __restrict__ B,
                        ushort_t* __restrict__ Vt) {
  constexpr int BM = 128, BN = 128, BK = 32, D = 1024;
  constexpr int WM = 64, WN = 64, MR = 4, NR = 4;
  __shared__ ushort_t lA[BM * BK];
  __shared__ ushort_t lB[BN * BK];
  const int m0 = blockIdx.y * BM, n0 = blockIdx.x * BN;
  const int tid = threadIdx.x, lane = tid & 63, wid = tid >> 6;
  const int wr = wid >> 1, wc = wid & 1;
  f32x4 acc[MR][NR] = {};
  for (int k0 = 0; k0 < D; k0 += BK) {
#pragma unroll
    for (int i = 0; i < 2; ++i) {
      int idx = i * 256 + tid;
      const float* g = A + (long long)(m0 + (idx >> 2)) * D + k0 + (idx & 3) * 8;
      *(uint4*)&lA[idx * 8] = cvt8(*(const float4*)g, *(const float4*)(g + 4));
    }
#pragma unroll
    for (int i = 0; i < 2; ++i) {
      int idx = i * 256 + tid;
      const float* g = B + (long long)(n0 + (idx >> 2)) * D + k0 + (idx & 3) * 8;
      *(uint4*)&lB[idx * 8] = cvt8(*(const float4*)g, *(const float4*)(g + 4));
    }
    __syncthreads();
    bf16x8 af[MR], bf[NR];
#pragma unroll
    for (int m = 0; m < MR; ++m)
      af[m] = *(const bf16x8*)&lA[(wr * WM + m * 16 + (lane & 15)) * BK + (lane >> 4) * 8];
#pragma unroll
    for (int n = 0; n < NR; ++n)
      bf[n] = *(const bf16x8*)&lB[(wc * WN + n * 16 + (lane & 15)) * BK + (lane >> 4) * 8];
#pragma unroll
    for (int m = 0; m < MR; ++m)
#pragma unroll
      for (int n = 0; n < NR; ++n)
        acc[m][n] = MFMA_16x16x32(af[m], bf[n], acc[m][n]);
    __syncthreads();
  }
#pragma unroll
  for (int m = 0; m < MR; ++m)
#pragma unroll
    for (int n = 0; n < NR; ++n) {
      int row = m0 + wr * WM + m * 16 + (lane >> 4) * 4;
      int col = n0 + wc * WN + n * 16 + (lane & 15);
      int b = row >> 10, s = row & 1023;
      int h = col >> 6, dk = col & 63;
      ushort4 pk;
      pk.x = f2bf(acc[m][n][0]);
      pk.y = f2bf(acc[m][n][1]);
      pk.z = f2bf(acc[m][n][2]);
      pk.w = f2bf(acc[m][n][3]);
      *(ushort4*)(Vt + ((long long)(b * 16 + h)) * 65536 + (long long)dk * 1024 + s) = pk;
    }
}

// ---------------------------------------------------------------------------
// FUSED attention v6: QBLK=16, 256 threads (4 waves), direct-reg K/V,
// LDS 33 KB -> 4 blocks/CU. attn f32 write moved INTO the PV phase
// (interleaves store traffic with MFMA). 3 barriers per block.
// ---------------------------------------------------------------------------
__launch_bounds__(256, 4)
__global__ void fused_attn(const ushort_t* __restrict__ Qp, const ushort_t* __restrict__ Kp,
                           const ushort_t* __restrict__ Vt, const int* __restrict__ mask,
                           float* __restrict__ attn, float* __restrict__ out) {
  constexpr int S = 1024, D = 1024;
  __shared__ ushort_t sc[16 * 1024];  // 32 KB bf16 scores -> exp values
  __shared__ float inv_s[16];
  __shared__ uchar_t ms[1024];

  // XCD-locality decode (neutral, kept for L2 working-set bound)
  const int n = blockIdx.x;            // 0..8191
  const int xcd = n & 7, s8 = n >> 3;  // 1024 per XCD
  const int bh = xcd + 8 * (s8 >> 6);  // 16 bh per XCD
  const int q0 = (s8 & 63) * 16;
  const int b = bh >> 4, h = bh & 15;
  const int t = threadIdx.x, lane = t & 63, w = t >> 6;

  {
    int4 mv = ((const int4*)(mask + b * S))[t];
    ms[t * 4 + 0] = (uchar_t)mv.x;
    ms[t * 4 + 1] = (uchar_t)mv.y;
    ms[t * 4 + 2] = (uchar_t)mv.z;
    ms[t * 4 + 3] = (uchar_t)mv.w;
  }

  // Q fragments for 16 q-rows, dk slice (lane>>4)*8 (+32)
  bf16x8 qa0, qa1;
  {
    const ushort_t* q =
        Qp + ((long long)(b * S + q0 + (lane & 15))) * D + h * 64 + (lane >> 4) * 8;
    qa0 = *(const bf16x8*)q;
    qa1 = *(const bf16x8*)(q + 32);
  }
  __syncthreads();  // ms ready

  // ---- Phase 1: QK^T. Wave w owns keys kb*64 + w*16 + (lane&15). ----
  {
    const ushort_t* kfb =
        Kp + ((long long)(b * S + w * 16 + (lane & 15))) * D + h * 64 + (lane >> 4) * 8;
#pragma unroll
    for (int kb = 0; kb < 16; ++kb) {
      const ushort_t* g = kfb + (long long)kb * 64 * D;
      bf16x8 kf0 = *(const bf16x8*)g;
      bf16x8 kf1 = *(const bf16x8*)(g + 32);
      f32x4 a0 = {};
      a0 = MFMA_16x16x32(qa0, kf0, a0);
      a0 = MFMA_16x16x32(qa1, kf1, a0);
      int key = kb * 64 + w * 16 + (lane & 15);
      bool valid = ms[key] != 0;
#pragma unroll
      for (int j = 0; j < 4; ++j)
        sc[sci32((lane >> 4) * 4 + j, key)] = f2bf(valid ? a0[j] * 0.125f : -30000.0f);
    }
  }
  __syncthreads();  // sc complete

  // ---- Phase 2: softmax stats only. thread (r = t>>4, c = t&15) ----
  {
    const int r = t >> 4, c = t & 15;
    float m = -3.0e38f;
#pragma unroll
    for (int i = 0; i < 16; ++i) {
      ushort4 sv = *(const ushort4*)&sc[sci32(r, c * 4 + i * 64)];
      m = fmaxf(m, fmaxf(fmaxf(bf2f(sv.x), bf2f(sv.y)), fmaxf(bf2f(sv.z), bf2f(sv.w))));
    }
#pragma unroll
    for (int off = 8; off; off >>= 1) m = fmaxf(m, __shfl_xor(m, off, 64));

    float sum = 0.f;
#pragma unroll
    for (int i = 0; i < 16; ++i) {
      int idx = sci32(r, c * 4 + i * 64);
      ushort4 sv = *(const ushort4*)&sc[idx];
      float p0 = __expf(bf2f(sv.x) - m);
      float p1 = __expf(bf2f(sv.y) - m);
      float p2 = __expf(bf2f(sv.z) - m);
      float p3 = __expf(bf2f(sv.w) - m);
      sum += (p0 + p1) + (p2 + p3);
      ushort4 pv;
      pv.x = f2bf(p0);
      pv.y = f2bf(p1);
      pv.z = f2bf(p2);
      pv.w = f2bf(p3);
      *(ushort4*)&sc[idx] = pv;  // unnormalized exp
    }
#pragma unroll
    for (int off = 8; off; off >>= 1) sum += __shfl_xor(sum, off, 64);
    if (c == 0) inv_s[r] = 1.0f / sum;
  }
  __syncthreads();  // exp in sc + inv_s final

  // ---- Phase 3: attn write (rows 4w..4w+3) interleaved with PV ----
  {
    // attn f32 writes: each wave owns 4 rows; coalesced float4 stores.
    float* abase = attn + ((long long)bh << 20) + ((long long)q0 << 10);
#pragma unroll
    for (int rr = 0; rr < 4; ++rr) {
      int r = w * 4 + rr;
      float inv = inv_s[r];
#pragma unroll
      for (int i = 0; i < 4; ++i) {
        int col = lane * 4 + i * 256;
        ushort4 pv = *(const ushort4*)&sc[sci32(r, col)];
        float4 o;
        o.x = bf2f(pv.x) * inv;
        o.y = bf2f(pv.y) * inv;
        o.z = bf2f(pv.z) * inv;
        o.w = bf2f(pv.w) * inv;
        *(float4*)&abase[((long long)r << 10) + col] = o;
      }
    }

    // PV: wave w = dk-tile dq; full K=1024 (32 chunks of 32).
    const int dq = w;
    f32x4 acc = {};
    const ushort_t* vfb = Vt + ((long long)bh << 16) +
                          ((long long)(dq * 16 + (lane & 15)) << 10) + (lane >> 4) * 8;
#pragma unroll
    for (int kc = 0; kc < 32; ++kc) {
      bf16x8 vb = *(const bf16x8*)(vfb + kc * 32);
      bf16x8 p0 = *(const bf16x8*)&sc[sci32(lane & 15, kc * 32 + (lane >> 4) * 8)];
      acc = MFMA_16x16x32(p0, vb, acc);
    }
    float* ob = out + ((long long)b << 20) + ((long long)q0 << 10) + h * 64 + dq * 16 +
                (lane & 15);
#pragma unroll
    for (int j = 0; j < 4; ++j) {
      int r = (lane >> 4) * 4 + j;
      ob[(long long)r << 10] = acc[j] * inv_s[r];
    }
  }
}

// ---------------------------------------------------------------------------
// Tier-C kernels (validated round 4): attn_scores f32 + gemm_pv
// ---------------------------------------------------------------------------
__launch_bounds__(256)
__global__ void attn_scores(const ushort_t* __restrict__ Qp, const ushort_t* __restrict__ Kp,
                            const int* __restrict__ mask, float* __restrict__ attn) {
  constexpr int S = 1024, D = 1024;
  __shared__ float scl[16][1028];
  __shared__ ushort_t ktl[64][72];
  const int q0 = blockIdx.x * 16;
  const int bh = blockIdx.y, b = bh >> 4, h = bh & 15;
  const int tid = threadIdx.x, lane = tid & 63, wid = tid >> 6;
  bf16x8 qa0, qa1;
  {
    const ushort_t* q =
        Qp + ((long long)(b * S + q0 + (lane & 15))) * D + h * 64 + (lane >> 4) * 8;
    qa0 = *(const bf16x8*)q;
    qa1 = *(const bf16x8*)(q + 32);
  }
  for (int kb = 0; kb < 16; ++kb) {
    {
      int r = tid >> 2, cg = (tid & 3) * 16;
      const ushort_t* g = Kp + ((long long)(b * S + kb * 64 + r)) * D + h * 64 + cg;
      *(uint4*)&ktl[r][cg] = *(const uint4*)g;
      *(uint4*)&ktl[r][cg + 8] = *(const uint4*)(g + 8);
    }
    __syncthreads();
    {
      int krow = wid * 16 + (lane & 15);
      bf16x8 b0 = *(const bf16x8*)&ktl[krow][(lane >> 4) * 8];
      bf16x8 b1 = *(const bf16x8*)&ktl[krow][32 + (lane >> 4) * 8];
      f32x4 acc = {};
      acc = MFMA_16x16x32(qa0, b0, acc);
      acc = MFMA_16x16x32(qa1, b1, acc);
      int key = kb * 64 + wid * 16 + (lane & 15);
      int mv = mask[b * S + key];
#pragma unroll
      for (int j = 0; j < 4; ++j)
        scl[(lane >> 4) * 4 + j][key] = mv ? acc[j] * 0.125f : -30000.0f;
    }
    __syncthreads();
  }
  for (int rr = 0; rr < 4; ++rr) {
    int r = wid * 4 + rr;
    float v[16];
    float mx = -3.0e38f;
#pragma unroll
    for (int i = 0; i < 16; ++i) {
      v[i] = scl[r][lane + i * 64];
      mx = fmaxf(mx, v[i]);
    }
#pragma unroll
    for (int off = 32; off; off >>= 1) mx = fmaxf(mx, __shfl_xor(mx, off, 64));
    float sum = 0.f;
#pragma unroll
    for (int i = 0; i < 16; ++i) {
      v[i] = __expf(v[i] - mx);
      sum += v[i];
    }
#pragma unroll
    for (int off = 32; off; off >>= 1) sum += __shfl_xor(sum, off, 64);
    float inv = 1.0f / sum;
    float* o = attn + (long long)bh * S * S + (long long)(q0 + r) * S + lane;
#pragma unroll
    for (int i = 0; i < 16; ++i) o[i * 64] = v[i] * inv;
  }
}

__launch_bounds__(256)
__global__ void gemm_pv(const float* __restrict__ attn, const ushort_t* __restrict__ Vt,
                        float* __restrict__ out) {
  constexpr int S = 1024, D = 1024;
  constexpr int BM = 128, BK = 32;
  constexpr int WM = 64, WN = 32, MR = 4, NR = 2;
  __shared__ ushort_t lA[BM * BK];
  __shared__ ushort_t lB[64 * BK];
  const int bh = blockIdx.z, b = bh >> 4, h = bh & 15;
  const float* A = attn + (long long)bh * S * S;
  const ushort_t* B = Vt + (long long)bh * 65536;
  float* C = out + (long long)b * S * D + h * 64;
  const int m0 = blockIdx.y * BM;
  const int tid = threadIdx.x, lane = tid & 63, wid = tid >> 6;
  const int wr = wid >> 1, wc = wid & 1;
  f32x4 acc[MR][NR] = {};
  for (int k0 = 0; k0 < S; k0 += BK) {
#pragma unroll
    for (int i = 0; i < 2; ++i) {
      int idx = i * 256 + tid;
      const float* g = A + (long long)(m0 + (idx >> 2)) * S + k0 + (idx & 3) * 8;
      *(uint4*)&lA[idx * 8] = cvt8(*(const float4*)g, *(const float4*)(g + 4));
    }
    {
      int row = tid >> 2, cg = (tid & 3) * 8;
      *(uint4*)&lB[row * BK + cg] = *(const uint4*)(B + (long long)row * S + k0 + cg);
    }
    __syncthreads();
    bf16x8 af[MR], bf[NR];
#pragma unroll
    for (int m = 0; m < MR; ++m)
      af[m] = *(const bf16x8*)&lA[(wr * WM + m * 16 + (lane & 15)) * BK + (lane >> 4) * 8];
#pragma unroll
    for (int n = 0; n < NR; ++n)
      bf[n] = *(const bf16x8*)&lB[(wc * WN + n * 16 + (lane & 15)) * BK + (lane >> 4) * 8];
#pragma unroll
    for (int m = 0; m < MR; ++m)
#pragma unroll
      for (int n = 0; n < NR; ++n)
        acc[m][n] = MFMA_16x16x32(af[m], bf[n], acc[m][n]);
    __syncthreads();
  }
#pragma unroll
  for (int m = 0; m < MR; ++m)
#pragma unroll
    for (int n = 0; n < NR; ++n)
#pragma unroll
      for (int j = 0; j < 4; ++j) {
        int row = m0 + wr * WM + m * 16 + (lane >> 4) * 4 + j;
        int col = wc * WN + n * 16 + (lane & 15);
        C[(long long)row * D + col] = acc[m][n][j];
      }
}

// ---------------------------------------------------------------------------
// Residual + LayerNorm, in-place on out (f32).
// ---------------------------------------------------------------------------
__launch_bounds__(256)
__global__ void ln_residual(const float* __restrict__ x, const float* __restrict__ gamma,
                            const float* __restrict__ beta, float* __restrict__ out) {
  constexpr int D = 1024;
  __shared__ float red[8];
  const int row = blockIdx.x;
  const int tid = threadIdx.x, lane = tid & 63, wid = tid >> 6;
  const int d0 = tid * 4;
  float4 xv = *(const float4*)(x + (long long)row * D + d0);
  float4 ov = *(const float4*)(out + (long long)row * D + d0);
  float v[4];
  v[0] = xv.x + ov.x;
  v[1] = xv.y + ov.y;
  v[2] = xv.z + ov.z;
  v[3] = xv.w + ov.w;
  float sum = v[0] + v[1] + v[2] + v[3];
  float sq = v[0] * v[0] + v[1] * v[1] + v[2] * v[2] + v[3] * v[3];
#pragma unroll
  for (int off = 32; off; off >>= 1) {
    sum += __shfl_xor(sum, off, 64);
    sq += __shfl_xor(sq, off, 64);
  }
  if (lane == 0) {
    red[wid] = sum;
    red[4 + wid] = sq;
  }
  __syncthreads();
  sum = red[0] + red[1] + red[2] + red[3];
  sq = red[4] + red[5] + red[6] + red[7];
  const float mu = sum * (1.0f / 1024.0f);
  const float var = sq * (1.0f / 1024.0f) - mu * mu;
  const float rs = rsqrtf(var + 1e-6f);
  float4 gv = *(const float4*)(gamma + d0);
  float4 bv = *(const float4*)(beta + d0);
  float4 r;
  r.x = (v[0] - mu) * rs * gv.x + bv.x;
  r.y = (v[1] - mu) * rs * gv.y + bv.y;
  r.z = (v[2] - mu) * rs * gv.z + bv.z;
  r.w = (v[3] - mu) * rs * gv.w + bv.w;
  *(float4*)(out + (long long)row * D + d0) = r;
}

// ---------------------------------------------------------------------------
extern "C" void kernel_launch(void* const* d_in, const int* in_sizes, int n_in,
                              void* d_out, int out_size, void* d_ws, size_t ws_size,
                              hipStream_t stream) {
  const int B = 8, S = 1024, D = 1024, H = 16;
  const float* x = (const float*)d_in[0];
  const int* mask = (const int*)d_in[1];
  const float* Wq = (const float*)d_in[2];
  const float* Wk = (const float*)d_in[3];
  const float* Wv = (const float*)d_in[4];
  const float* gamma = (const float*)d_in[5];
  const float* beta = (const float*)d_in[6];

  float* attn = (float*)d_out;
  float* out = attn + (long long)B * H * S * S;

  const long long BSD = (long long)B * S * D;
  const long long DDe = (long long)D * D;
  const size_t MB = 1u << 20;
  ushort_t* ws = (ushort_t*)d_ws;

  if (ws_size >= 70 * MB) {
    // Tier A: all-bf16 (m97 gload GEMMs)
    ushort_t* xb = ws;
    ushort_t* Wqb = xb + BSD;
    ushort_t* Wkb = Wqb + DDe;
    ushort_t* Wvb = Wkb + DDe;
    ushort_t* Qp = Wvb + DDe;
    ushort_t* Kp = Qp + BSD;
    ushort_t* Vt = Kp + BSD;
    cvt_f32_bf16<<<dim3((int)(BSD / 4 / 256)), 256, 0, stream>>>(x, xb, (int)(BSD / 4));
    cvt_f32_bf16<<<dim3((int)(DDe / 4 / 256)), 256, 0, stream>>>(Wq, Wqb, (int)(DDe / 4));
    cvt_f32_bf16<<<dim3((int)(DDe / 4 / 256)), 256, 0, stream>>>(Wk, Wkb, (int)(DDe / 4));
    cvt_f32_bf16<<<dim3((int)(DDe / 4 / 256)), 256, 0, stream>>>(Wv, Wvb, (int)(DDe / 4));
    gemm_bt<false><<<dim3(D / 128, (B * S) / 128), 256, 0, stream>>>(xb, Wqb, Qp);
    gemm_bt<false><<<dim3(D / 128, (B * S) / 128), 256, 0, stream>>>(xb, Wkb, Kp);
    gemm_bt<true><<<dim3(D / 128, (B * S) / 128), 256, 0, stream>>>(xb, Wvb, Vt);
    fused_attn<<<dim3((S / 16) * B * H), 256, 0, stream>>>(Qp, Kp, Vt, mask, attn, out);
    ln_residual<<<dim3(B * S), 256, 0, stream>>>(x, gamma, beta, out);
  } else if (ws_size >= 48 * MB) {
    // Tier B: f32-staged projections + fused attention
    ushort_t* Qp = ws;
    ushort_t* Kp = Qp + BSD;
    ushort_t* Vt = Kp + BSD;
    gemm_proj<<<dim3(D / 128, (B * S) / 128), 256, 0, stream>>>(x, Wq, Qp, D, D, D, D);
    gemm_proj<<<dim3(D / 128, (B * S) / 128), 256, 0, stream>>>(x, Wk, Kp, D, D, D, D);
    gemm_vt<<<dim3(D / 128, (B * S) / 128), 256, 0, stream>>>(x, Wv, Vt);
    fused_attn<<<dim3((S / 16) * B * H), 256, 0, stream>>>(Qp, Kp, Vt, mask, attn, out);
    ln_residual<<<dim3(B * S), 256, 0, stream>>>(x, gamma, beta, out);
  } else {
    // Tier C: validated round-4 pipeline
    ushort_t* Qp = ws;
    ushort_t* Kp = Qp + BSD;
    ushort_t* Vt = Qp;
    gemm_proj<<<dim3(D / 128, (B * S) / 128), 256, 0, stream>>>(x, Wq, Qp, D, D, D, D);
    gemm_proj<<<dim3(D / 128, (B * S) / 128), 256, 0, stream>>>(x, Wk, Kp, D, D, D, D);
    attn_scores<<<dim3(S / 16, B * H), 256, 0, stream>>>(Qp, Kp, mask, attn);
    gemm_vt<<<dim3(D / 128, (B * S) / 128), 256, 0, stream>>>(x, Wv, Vt);
    gemm_pv<<<dim3(1, S / 128, B * H), 256, 0, stream>>>(attn, Vt, out);
    ln_residual<<<dim3(B * S), 256, 0, stream>>>(x, gamma, beta, out);
  }
}

// Round 11
// 293.820 us; speedup vs baseline: 1.4701x; 1.4701x over previous
//
#include <hip/hip_runtime.h>

typedef __bf16 bf16x8 __attribute__((ext_vector_type(8)));
typedef float f32x4 __attribute__((ext_vector_type(4)));
typedef unsigned short ushort_t;
typedef unsigned char uchar_t;

#define MFMA_16x16x32(A, B, C) __builtin_amdgcn_mfma_f32_16x16x32_bf16(A, B, C, 0, 0, 0)

__device__ __forceinline__ float bf2f(ushort_t u) {
  unsigned int x = ((unsigned int)u) << 16;
  float f;
  __builtin_memcpy(&f, &x, 4);
  return f;
}
__device__ __forceinline__ ushort_t f2bf(float f) {
  unsigned int x;
  __builtin_memcpy(&x, &f, 4);
  x = x + 0x7fffu + ((x >> 16) & 1u);
  return (ushort_t)(x >> 16);
}
__device__ __forceinline__ ushort_t f2bf_s(float f) {
  if (!(__builtin_fabsf(f) < 3.0e38f)) f = 0.0f;
  return f2bf(f);
}

__device__ __forceinline__ void gload_lds16(const void* g, void* l) {
  __builtin_amdgcn_global_load_lds(
      (__attribute__((address_space(1))) void*)const_cast<void*>(g),
      (__attribute__((address_space(3))) void*)l, 16, 0, 0);
}

__device__ __forceinline__ uint4 cvt8(float4 a, float4 b) {
  uint4 r;
  r.x = (unsigned)f2bf_s(a.x) | ((unsigned)f2bf_s(a.y) << 16);
  r.y = (unsigned)f2bf_s(a.z) | ((unsigned)f2bf_s(a.w) << 16);
  r.z = (unsigned)f2bf_s(b.x) | ((unsigned)f2bf_s(b.y) << 16);
  r.w = (unsigned)f2bf_s(b.z) | ((unsigned)f2bf_s(b.w) << 16);
  return r;
}

// XOR-granule swizzle (granule = 8 bf16 = 16B) for [R][1024] bf16 buffer.
__device__ __forceinline__ int sci32(int r, int col) {
  int g = col >> 3;
  g = (g & ~7) | ((g ^ r) & 7);
  return (r << 10) + (g << 3) + (col & 7);
}

// ---------------------------------------------------------------------------
// f32 -> bf16 bulk convert (sanitizing), 4 elems/thread
// ---------------------------------------------------------------------------
__launch_bounds__(256)
__global__ void cvt_f32_bf16(const float* __restrict__ in, ushort_t* __restrict__ out, int n4) {
  int i = blockIdx.x * 256 + threadIdx.x;
  if (i >= n4) return;
  float4 v = ((const float4*)in)[i];
  ushort4 r;
  r.x = f2bf_s(v.x);
  r.y = f2bf_s(v.y);
  r.z = f2bf_s(v.z);
  r.w = f2bf_s(v.w);
  ((ushort4*)out)[i] = r;
}

// ---------------------------------------------------------------------------
// Fused QKV projection GEMM (bf16, m97 structure, global_load_lds w16).
// One dispatch; blockIdx.z in {0,1,2} selects {Wq->Qp, Wk->Kp, Wv->Vt(scatter)}.
// C[m,n] = sum_k xb[m,k] * W[n,k]; M=8192, N=1024, K=1024, 128^2 tiles.
// ---------------------------------------------------------------------------
__launch_bounds__(256)
__global__ void gemm_qkv(const ushort_t* __restrict__ xb, const ushort_t* __restrict__ Wq,
                         const ushort_t* __restrict__ Wk, const ushort_t* __restrict__ Wv,
                         ushort_t* __restrict__ Qp, ushort_t* __restrict__ Kp,
                         ushort_t* __restrict__ Vt) {
  constexpr int BK = 32, LD = 1024, K = 1024;
  constexpr int WM = 64, WN = 64, MR = 4, NR = 4;

  __shared__ ushort_t lA[128 * BK];
  __shared__ ushort_t lB[128 * BK];

  const int z = blockIdx.z;
  const ushort_t* B = (z == 0) ? Wq : (z == 1) ? Wk : Wv;

  const int m0 = blockIdx.y * 128;
  const int n0 = blockIdx.x * 128;
  const int tid = threadIdx.x;
  const int lane = tid & 63, wid = tid >> 6;
  const int wr = wid >> 1, wc = wid & 1;

  f32x4 acc[MR][NR] = {};

  for (int k0 = 0; k0 < K; k0 += BK) {
#pragma unroll
    for (int i = 0; i < 2; ++i) {
      int idx = i * 256 + tid;
      const ushort_t* g = xb + (long long)(m0 + (idx >> 2)) * LD + k0 + (idx & 3) * 8;
      gload_lds16(g, (void*)(lA + (i * 256 + wid * 64) * 8));
    }
#pragma unroll
    for (int i = 0; i < 2; ++i) {
      int idx = i * 256 + tid;
      const ushort_t* g = B + (long long)(n0 + (idx >> 2)) * LD + k0 + (idx & 3) * 8;
      gload_lds16(g, (void*)(lB + (i * 256 + wid * 64) * 8));
    }
    __syncthreads();

    bf16x8 af[MR], bf[NR];
#pragma unroll
    for (int m = 0; m < MR; ++m)
      af[m] = *(const bf16x8*)&lA[(wr * WM + m * 16 + (lane & 15)) * BK + (lane >> 4) * 8];
#pragma unroll
    for (int n = 0; n < NR; ++n)
      bf[n] = *(const bf16x8*)&lB[(wc * WN + n * 16 + (lane & 15)) * BK + (lane >> 4) * 8];
#pragma unroll
    for (int m = 0; m < MR; ++m)
#pragma unroll
      for (int n = 0; n < NR; ++n)
        acc[m][n] = MFMA_16x16x32(af[m], bf[n], acc[m][n]);
    __syncthreads();
  }

  if (z < 2) {
    ushort_t* C = (z == 0) ? Qp : Kp;
#pragma unroll
    for (int m = 0; m < MR; ++m)
#pragma unroll
      for (int n = 0; n < NR; ++n)
#pragma unroll
        for (int j = 0; j < 4; ++j) {
          int row = m0 + wr * WM + m * 16 + (lane >> 4) * 4 + j;
          int col = n0 + wc * WN + n * 16 + (lane & 15);
          C[(long long)row * LD + col] = f2bf(acc[m][n][j]);
        }
  } else {
#pragma unroll
    for (int m = 0; m < MR; ++m)
#pragma unroll
      for (int n = 0; n < NR; ++n) {
        int row = m0 + wr * WM + m * 16 + (lane >> 4) * 4;
        int col = n0 + wc * WN + n * 16 + (lane & 15);
        int b = row >> 10, s = row & 1023;
        int h = col >> 6, dk = col & 63;
        ushort4 pk;
        pk.x = f2bf(acc[m][n][0]);
        pk.y = f2bf(acc[m][n][1]);
        pk.z = f2bf(acc[m][n][2]);
        pk.w = f2bf(acc[m][n][3]);
        *(ushort4*)(Vt + ((long long)(b * 16 + h)) * 65536 + (long long)dk * 1024 + s) = pk;
      }
  }
}

// ---------------------------------------------------------------------------
// f32-input projection GEMM (fallback tiers) — validated round 4.
// ---------------------------------------------------------------------------
__launch_bounds__(256)
__global__ void gemm_proj(const float* __restrict__ A, const float* __restrict__ B,
                          ushort_t* __restrict__ C, int K, int lda, int ldb, int ldc) {
  constexpr int BM = 128, BN = 128, BK = 32;
  constexpr int WM = 64, WN = 64, MR = 4, NR = 4;
  __shared__ ushort_t lA[BM * BK];
  __shared__ ushort_t lB[BN * BK];
  const int m0 = blockIdx.y * BM, n0 = blockIdx.x * BN;
  const int tid = threadIdx.x, lane = tid & 63, wid = tid >> 6;
  const int wr = wid >> 1, wc = wid & 1;
  f32x4 acc[MR][NR] = {};
  for (int k0 = 0; k0 < K; k0 += BK) {
#pragma unroll
    for (int i = 0; i < 2; ++i) {
      int idx = i * 256 + tid;
      const float* g = A + (long long)(m0 + (idx >> 2)) * lda + k0 + (idx & 3) * 8;
      *(uint4*)&lA[idx * 8] = cvt8(*(const float4*)g, *(const float4*)(g + 4));
    }
#pragma unroll
    for (int i = 0; i < 2; ++i) {
      int idx = i * 256 + tid;
      const float* g = B + (long long)(n0 + (idx >> 2)) * ldb + k0 + (idx & 3) * 8;
      *(uint4*)&lB[idx * 8] = cvt8(*(const float4*)g, *(const float4*)(g + 4));
    }
    __syncthreads();
    bf16x8 af[MR], bf[NR];
#pragma unroll
    for (int m = 0; m < MR; ++m)
      af[m] = *(const bf16x8*)&lA[(wr * WM + m * 16 + (lane & 15)) * BK + (lane >> 4) * 8];
#pragma unroll
    for (int n = 0; n < NR; ++n)
      bf[n] = *(const bf16x8*)&lB[(wc * WN + n * 16 + (lane & 15)) * BK + (lane >> 4) * 8];
#pragma unroll
    for (int m = 0; m < MR; ++m)
#pragma unroll
      for (int n = 0; n < NR; ++n)
        acc[m][n] = MFMA_16x16x32(af[m], bf[n], acc[m][n]);
    __syncthreads();
  }
#pragma unroll
  for (int m = 0; m < MR; ++m)
#pragma unroll
    for (int n = 0; n < NR; ++n)
#pragma unroll
      for (int j = 0; j < 4; ++j) {
        int row = m0 + wr * WM + m * 16 + (lane >> 4) * 4 + j;
        int col = n0 + wc * WN + n * 16 + (lane & 15);
        C[(long long)row * ldc + col] = f2bf(acc[m][n][j]);
      }
}

// f32-input V projection with transpose-scatter epilogue — validated round 4.
__launch_bounds__(256)
__global__ void gemm_vt(const float* __restrict__ A, const float* __restrict__ B,
                        ushort_t* __restrict__ Vt) {
  constexpr int BM = 128, BN = 128, BK = 32, D = 1024;
  constexpr int WM = 64, WN = 64, MR = 4, NR = 4;
  __shared__ ushort_t lA[BM * BK];
  __shared__ ushort_t lB[BN * BK];
  const int m0 = blockIdx.y * BM, n0 = blockIdx.x * BN;
  const int tid = threadIdx.x, lane = tid & 63, wid = tid >> 6;
  const int wr = wid >> 1, wc = wid & 1;
  f32x4 acc[MR][NR] = {};
  for (int k0 = 0; k0 < D; k0 += BK) {
#pragma unroll
    for (int i = 0; i < 2; ++i) {
      int idx = i * 256 + tid;
      const float* g = A + (long long)(m0 + (idx >> 2)) * D + k0 + (idx & 3) * 8;
      *(uint4*)&lA[idx * 8] = cvt8(*(const float4*)g, *(const float4*)(g + 4));
    }
#pragma unroll
    for (int i = 0; i < 2; ++i) {
      int idx = i * 256 + tid;
      const float* g = B + (long long)(n0 + (idx >> 2)) * D + k0 + (idx & 3) * 8;
      *(uint4*)&lB[idx * 8] = cvt8(*(const float4*)g, *(const float4*)(g + 4));
    }
    __syncthreads();
    bf16x8 af[MR], bf[NR];
#pragma unroll
    for (int m = 0; m < MR; ++m)
      af[m] = *(const bf16x8*)&lA[(wr * WM + m * 16 + (lane & 15)) * BK + (lane >> 4) * 8];
#pragma unroll
    for (int n = 0; n < NR; ++n)
      bf[n] = *(const bf16x8*)&lB[(wc * WN + n * 16 + (lane & 15)) * BK + (lane >> 4) * 8];
#pragma unroll
    for (int m = 0; m < MR; ++m)
#pragma unroll
      for (int n = 0; n < NR; ++n)
        acc[m][n] = MFMA_16x16x32(af[m], bf[n], acc[m][n]);
    __syncthreads();
  }
#pragma unroll
  for (int m = 0; m < MR; ++m)
#pragma unroll
    for (int n = 0; n < NR; ++n) {
      int row = m0 + wr * WM + m * 16 + (lane >> 4) * 4;
      int col = n0 + wc * WN + n * 16 + (lane & 15);
      int b = row >> 10, s = row & 1023;
      int h = col >> 6, dk = col & 63;
      ushort4 pk;
      pk.x = f2bf(acc[m][n][0]);
      pk.y = f2bf(acc[m][n][1]);
      pk.z = f2bf(acc[m][n][2]);
      pk.w = f2bf(acc[m][n][3]);
      *(ushort4*)(Vt + ((long long)(b * 16 + h)) * 65536 + (long long)dk * 1024 + s) = pk;
    }
}

// ---------------------------------------------------------------------------
// FUSED attention v7 = v4 (round-8 champion: QBLK=32, 512 threads, direct
// global->register K/V, 4 barriers, 2-chain PV) + NON-TEMPORAL stores for
// the streaming attn/out writes (bypass L2 -> keep K/V resident).
// ---------------------------------------------------------------------------
__launch_bounds__(512, 4)
__global__ void fused_attn(const ushort_t* __restrict__ Qp, const ushort_t* __restrict__ Kp,
                           const ushort_t* __restrict__ Vt, const int* __restrict__ mask,
                           float* __restrict__ attn, float* __restrict__ out) {
  constexpr int S = 1024, D = 1024;
  __shared__ ushort_t sc[32 * 1024];  // 64 KB bf16 scores -> exp values
  __shared__ float red[2048];         // 8 KB cross-kh PV partials
  __shared__ float inv_s[32];
  __shared__ uchar_t ms[1024];

  const int q0 = blockIdx.x * 32;
  const int bh = blockIdx.y, b = bh >> 4, h = bh & 15;
  const int t = threadIdx.x, lane = t & 63, w = t >> 6;

  if (t < 256) {
    int4 mv = ((const int4*)(mask + b * S))[t];
    ms[t * 4 + 0] = (uchar_t)mv.x;
    ms[t * 4 + 1] = (uchar_t)mv.y;
    ms[t * 4 + 2] = (uchar_t)mv.z;
    ms[t * 4 + 3] = (uchar_t)mv.w;
  }

  // Q fragments for the 32 q-rows (2 halves), dk slice (lane>>4)*8 (+32)
  bf16x8 qa00, qa01, qa10, qa11;
  {
    const ushort_t* q =
        Qp + ((long long)(b * S + q0 + (lane & 15))) * D + h * 64 + (lane >> 4) * 8;
    qa00 = *(const bf16x8*)q;
    qa01 = *(const bf16x8*)(q + 32);
    qa10 = *(const bf16x8*)(q + 16 * D);
    qa11 = *(const bf16x8*)(q + 16 * D + 32);
  }
  __syncthreads();  // ms ready

  // ---- Phase 1: QK^T. Wave w owns keys kb*128 + w*16 + (lane&15). ----
  {
    const ushort_t* kfb =
        Kp + ((long long)(b * S + w * 16 + (lane & 15))) * D + h * 64 + (lane >> 4) * 8;
#pragma unroll
    for (int kb = 0; kb < 8; ++kb) {
      const ushort_t* g = kfb + (long long)kb * 128 * D;
      bf16x8 kf0 = *(const bf16x8*)g;
      bf16x8 kf1 = *(const bf16x8*)(g + 32);
      f32x4 a0 = {}, a1 = {};
      a0 = MFMA_16x16x32(qa00, kf0, a0);
      a0 = MFMA_16x16x32(qa01, kf1, a0);
      a1 = MFMA_16x16x32(qa10, kf0, a1);
      a1 = MFMA_16x16x32(qa11, kf1, a1);
      int key = kb * 128 + w * 16 + (lane & 15);
      bool valid = ms[key] != 0;
#pragma unroll
      for (int j = 0; j < 4; ++j) {
        int r = (lane >> 4) * 4 + j;
        sc[sci32(r, key)] = f2bf(valid ? a0[j] * 0.125f : -30000.0f);
        sc[sci32(16 + r, key)] = f2bf(valid ? a1[j] * 0.125f : -30000.0f);
      }
    }
  }
  __syncthreads();  // sc complete

  // ---- Phase 2: softmax. thread (r = t>>4, c = t&15): 64 elems of row r ----
  {
    const int r = t >> 4, c = t & 15;
    float m = -3.0e38f;
#pragma unroll
    for (int i = 0; i < 16; ++i) {
      ushort4 sv = *(const ushort4*)&sc[sci32(r, c * 4 + i * 64)];
      m = fmaxf(m, fmaxf(fmaxf(bf2f(sv.x), bf2f(sv.y)), fmaxf(bf2f(sv.z), bf2f(sv.w))));
    }
#pragma unroll
    for (int off = 8; off; off >>= 1) m = fmaxf(m, __shfl_xor(m, off, 64));

    float sum = 0.f;
#pragma unroll
    for (int i = 0; i < 16; ++i) {
      int idx = sci32(r, c * 4 + i * 64);
      ushort4 sv = *(const ushort4*)&sc[idx];
      float p0 = __expf(bf2f(sv.x) - m);
      float p1 = __expf(bf2f(sv.y) - m);
      float p2 = __expf(bf2f(sv.z) - m);
      float p3 = __expf(bf2f(sv.w) - m);
      sum += (p0 + p1) + (p2 + p3);
      ushort4 pv;
      pv.x = f2bf(p0);
      pv.y = f2bf(p1);
      pv.z = f2bf(p2);
      pv.w = f2bf(p3);
      *(ushort4*)&sc[idx] = pv;  // unnormalized exp (own cells only)
    }
#pragma unroll
    for (int off = 8; off; off >>= 1) sum += __shfl_xor(sum, off, 64);
    float inv = 1.0f / sum;
    if (c == 0) inv_s[r] = inv;

    float* arow = attn + ((long long)bh << 20) + ((long long)(q0 + r) << 10);
#pragma unroll
    for (int i = 0; i < 16; ++i) {
      ushort4 pv = *(const ushort4*)&sc[sci32(r, c * 4 + i * 64)];
      f32x4 o;
      o[0] = bf2f(pv.x) * inv;
      o[1] = bf2f(pv.y) * inv;
      o[2] = bf2f(pv.z) * inv;
      o[3] = bf2f(pv.w) * inv;
      __builtin_nontemporal_store(o, (f32x4*)&arow[c * 4 + i * 64]);
    }
  }
  __syncthreads();  // exp in sc + inv_s final

  // ---- Phase 3: PV. wave (dq = w&3 dk-tile, kh = w>>2 K-half) ----
  {
    const int dq = w & 3, kh = w >> 2;
    f32x4 acc0 = {}, acc1 = {};
    const ushort_t* vfb = Vt + ((long long)bh << 16) +
                          ((long long)(dq * 16 + (lane & 15)) << 10) + kh * 512 +
                          (lane >> 4) * 8;
#pragma unroll
    for (int kc = 0; kc < 16; ++kc) {
      bf16x8 vb = *(const bf16x8*)(vfb + kc * 32);
      int kslice = kh * 512 + kc * 32 + (lane >> 4) * 8;
      bf16x8 p0 = *(const bf16x8*)&sc[sci32(lane & 15, kslice)];
      bf16x8 p1 = *(const bf16x8*)&sc[sci32(16 + (lane & 15), kslice)];
      acc0 = MFMA_16x16x32(p0, vb, acc0);
      acc1 = MFMA_16x16x32(p1, vb, acc1);
    }
    if (kh == 1) {
      *(f32x4*)&red[((dq * 2 + 0) * 64 + lane) * 4] = acc0;
      *(f32x4*)&red[((dq * 2 + 1) * 64 + lane) * 4] = acc1;
    }
    __syncthreads();  // red ready
    if (kh == 0) {
      f32x4 o0 = *(const f32x4*)&red[((dq * 2 + 0) * 64 + lane) * 4];
      f32x4 o1 = *(const f32x4*)&red[((dq * 2 + 1) * 64 + lane) * 4];
      float* ob = out + ((long long)b << 20) + ((long long)q0 << 10) + h * 64 + dq * 16 +
                  (lane & 15);
#pragma unroll
      for (int j = 0; j < 4; ++j) {
        int r0 = (lane >> 4) * 4 + j;
        int r1 = 16 + r0;
        __builtin_nontemporal_store((acc0[j] + o0[j]) * inv_s[r0], &ob[(long long)r0 << 10]);
        __builtin_nontemporal_store((acc1[j] + o1[j]) * inv_s[r1], &ob[(long long)r1 << 10]);
      }
    }
  }
}

// ---------------------------------------------------------------------------
// Tier-C kernels (validated round 4): attn_scores f32 + gemm_pv
// ---------------------------------------------------------------------------
__launch_bounds__(256)
__global__ void attn_scores(const ushort_t* __restrict__ Qp, const ushort_t* __restrict__ Kp,
                            const int* __restrict__ mask, float* __restrict__ attn) {
  constexpr int S = 1024, D = 1024;
  __shared__ float scl[16][1028];
  __shared__ ushort_t ktl[64][72];
  const int q0 = blockIdx.x * 16;
  const int bh = blockIdx.y, b = bh >> 4, h = bh & 15;
  const int tid = threadIdx.x, lane = tid & 63, wid = tid >> 6;
  bf16x8 qa0, qa1;
  {
    const ushort_t* q =
        Qp + ((long long)(b * S + q0 + (lane & 15))) * D + h * 64 + (lane >> 4) * 8;
    qa0 = *(const bf16x8*)q;
    qa1 = *(const bf16x8*)(q + 32);
  }
  for (int kb = 0; kb < 16; ++kb) {
    {
      int r = tid >> 2, cg = (tid & 3) * 16;
      const ushort_t* g = Kp + ((long long)(b * S + kb * 64 + r)) * D + h * 64 + cg;
      *(uint4*)&ktl[r][cg] = *(const uint4*)g;
      *(uint4*)&ktl[r][cg + 8] = *(const uint4*)(g + 8);
    }
    __syncthreads();
    {
      int krow = wid * 16 + (lane & 15);
      bf16x8 b0 = *(const bf16x8*)&ktl[krow][(lane >> 4) * 8];
      bf16x8 b1 = *(const bf16x8*)&ktl[krow][32 + (lane >> 4) * 8];
      f32x4 acc = {};
      acc = MFMA_16x16x32(qa0, b0, acc);
      acc = MFMA_16x16x32(qa1, b1, acc);
      int key = kb * 64 + wid * 16 + (lane & 15);
      int mv = mask[b * S + key];
#pragma unroll
      for (int j = 0; j < 4; ++j)
        scl[(lane >> 4) * 4 + j][key] = mv ? acc[j] * 0.125f : -30000.0f;
    }
    __syncthreads();
  }
  for (int rr = 0; rr < 4; ++rr) {
    int r = wid * 4 + rr;
    float v[16];
    float mx = -3.0e38f;
#pragma unroll
    for (int i = 0; i < 16; ++i) {
      v[i] = scl[r][lane + i * 64];
      mx = fmaxf(mx, v[i]);
    }
#pragma unroll
    for (int off = 32; off; off >>= 1) mx = fmaxf(mx, __shfl_xor(mx, off, 64));
    float sum = 0.f;
#pragma unroll
    for (int i = 0; i < 16; ++i) {
      v[i] = __expf(v[i] - mx);
      sum += v[i];
    }
#pragma unroll
    for (int off = 32; off; off >>= 1) sum += __shfl_xor(sum, off, 64);
    float inv = 1.0f / sum;
    float* o = attn + (long long)bh * S * S + (long long)(q0 + r) * S + lane;
#pragma unroll
    for (int i = 0; i < 16; ++i) o[i * 64] = v[i] * inv;
  }
}

__launch_bounds__(256)
__global__ void gemm_pv(const float* __restrict__ attn, const ushort_t* __restrict__ Vt,
                        float* __restrict__ out) {
  constexpr int S = 1024, D = 1024;
  constexpr int BM = 128, BK = 32;
  constexpr int WM = 64, WN = 32, MR = 4, NR = 2;
  __shared__ ushort_t lA[BM * BK];
  __shared__ ushort_t lB[64 * BK];
  const int bh = blockIdx.z, b = bh >> 4, h = bh & 15;
  const float* A = attn + (long long)bh * S * S;
  const ushort_t* B = Vt + (long long)bh * 65536;
  float* C = out + (long long)b * S * D + h * 64;
  const int m0 = blockIdx.y * BM;
  const int tid = threadIdx.x, lane = tid & 63, wid = tid >> 6;
  const int wr = wid >> 1, wc = wid & 1;
  f32x4 acc[MR][NR] = {};
  for (int k0 = 0; k0 < S; k0 += BK) {
#pragma unroll
    for (int i = 0; i < 2; ++i) {
      int idx = i * 256 + tid;
      const float* g = A + (long long)(m0 + (idx >> 2)) * S + k0 + (idx & 3) * 8;
      *(uint4*)&lA[idx * 8] = cvt8(*(const float4*)g, *(const float4*)(g + 4));
    }
    {
      int row = tid >> 2, cg = (tid & 3) * 8;
      *(uint4*)&lB[row * BK + cg] = *(const uint4*)(B + (long long)row * S + k0 + cg);
    }
    __syncthreads();
    bf16x8 af[MR], bf[NR];
#pragma unroll
    for (int m = 0; m < MR; ++m)
      af[m] = *(const bf16x8*)&lA[(wr * WM + m * 16 + (lane & 15)) * BK + (lane >> 4) * 8];
#pragma unroll
    for (int n = 0; n < NR; ++n)
      bf[n] = *(const bf16x8*)&lB[(wc * WN + n * 16 + (lane & 15)) * BK + (lane >> 4) * 8];
#pragma unroll
    for (int m = 0; m < MR; ++m)
#pragma unroll
      for (int n = 0; n < NR; ++n)
        acc[m][n] = MFMA_16x16x32(af[m], bf[n], acc[m][n]);
    __syncthreads();
  }
#pragma unroll
  for (int m = 0; m < MR; ++m)
#pragma unroll
    for (int n = 0; n < NR; ++n)
#pragma unroll
      for (int j = 0; j < 4; ++j) {
        int row = m0 + wr * WM + m * 16 + (lane >> 4) * 4 + j;
        int col = wc * WN + n * 16 + (lane & 15);
        C[(long long)row * D + col] = acc[m][n][j];
      }
}

// ---------------------------------------------------------------------------
// Residual + LayerNorm, in-place on out (f32).
// ---------------------------------------------------------------------------
__launch_bounds__(256)
__global__ void ln_residual(const float* __restrict__ x, const float* __restrict__ gamma,
                            const float* __restrict__ beta, float* __restrict__ out) {
  constexpr int D = 1024;
  __shared__ float red[8];
  const int row = blockIdx.x;
  const int tid = threadIdx.x, lane = tid & 63, wid = tid >> 6;
  const int d0 = tid * 4;
  float4 xv = *(const float4*)(x + (long long)row * D + d0);
  float4 ov = *(const float4*)(out + (long long)row * D + d0);
  float v[4];
  v[0] = xv.x + ov.x;
  v[1] = xv.y + ov.y;
  v[2] = xv.z + ov.z;
  v[3] = xv.w + ov.w;
  float sum = v[0] + v[1] + v[2] + v[3];
  float sq = v[0] * v[0] + v[1] * v[1] + v[2] * v[2] + v[3] * v[3];
#pragma unroll
  for (int off = 32; off; off >>= 1) {
    sum += __shfl_xor(sum, off, 64);
    sq += __shfl_xor(sq, off, 64);
  }
  if (lane == 0) {
    red[wid] = sum;
    red[4 + wid] = sq;
  }
  __syncthreads();
  sum = red[0] + red[1] + red[2] + red[3];
  sq = red[4] + red[5] + red[6] + red[7];
  const float mu = sum * (1.0f / 1024.0f);
  const float var = sq * (1.0f / 1024.0f) - mu * mu;
  const float rs = rsqrtf(var + 1e-6f);
  float4 gv = *(const float4*)(gamma + d0);
  float4 bv = *(const float4*)(beta + d0);
  f32x4 r;
  r[0] = (v[0] - mu) * rs * gv.x + bv.x;
  r[1] = (v[1] - mu) * rs * gv.y + bv.y;
  r[2] = (v[2] - mu) * rs * gv.z + bv.z;
  r[3] = (v[3] - mu) * rs * gv.w + bv.w;
  __builtin_nontemporal_store(r, (f32x4*)(out + (long long)row * D + d0));
}

// ---------------------------------------------------------------------------
extern "C" void kernel_launch(void* const* d_in, const int* in_sizes, int n_in,
                              void* d_out, int out_size, void* d_ws, size_t ws_size,
                              hipStream_t stream) {
  const int B = 8, S = 1024, D = 1024, H = 16;
  const float* x = (const float*)d_in[0];
  const int* mask = (const int*)d_in[1];
  const float* Wq = (const float*)d_in[2];
  const float* Wk = (const float*)d_in[3];
  const float* Wv = (const float*)d_in[4];
  const float* gamma = (const float*)d_in[5];
  const float* beta = (const float*)d_in[6];

  float* attn = (float*)d_out;
  float* out = attn + (long long)B * H * S * S;

  const long long BSD = (long long)B * S * D;
  const long long DDe = (long long)D * D;
  const size_t MB = 1u << 20;
  ushort_t* ws = (ushort_t*)d_ws;

  if (ws_size >= 70 * MB) {
    // Tier A: all-bf16 (m97 gload GEMMs), single fused QKV dispatch
    ushort_t* xb = ws;
    ushort_t* Wqb = xb + BSD;
    ushort_t* Wkb = Wqb + DDe;
    ushort_t* Wvb = Wkb + DDe;
    ushort_t* Qp = Wvb + DDe;
    ushort_t* Kp = Qp + BSD;
    ushort_t* Vt = Kp + BSD;
    cvt_f32_bf16<<<dim3((int)(BSD / 4 / 256)), 256, 0, stream>>>(x, xb, (int)(BSD / 4));
    cvt_f32_bf16<<<dim3((int)(DDe / 4 / 256)), 256, 0, stream>>>(Wq, Wqb, (int)(DDe / 4));
    cvt_f32_bf16<<<dim3((int)(DDe / 4 / 256)), 256, 0, stream>>>(Wk, Wkb, (int)(DDe / 4));
    cvt_f32_bf16<<<dim3((int)(DDe / 4 / 256)), 256, 0, stream>>>(Wv, Wvb, (int)(DDe / 4));
    gemm_qkv<<<dim3(D / 128, (B * S) / 128, 3), 256, 0, stream>>>(xb, Wqb, Wkb, Wvb, Qp, Kp,
                                                                  Vt);
    fused_attn<<<dim3(S / 32, B * H), 512, 0, stream>>>(Qp, Kp, Vt, mask, attn, out);
    ln_residual<<<dim3(B * S), 256, 0, stream>>>(x, gamma, beta, out);
  } else if (ws_size >= 48 * MB) {
    // Tier B: f32-staged projections + fused attention
    ushort_t* Qp = ws;
    ushort_t* Kp = Qp + BSD;
    ushort_t* Vt = Kp + BSD;
    gemm_proj<<<dim3(D / 128, (B * S) / 128), 256, 0, stream>>>(x, Wq, Qp, D, D, D, D);
    gemm_proj<<<dim3(D / 128, (B * S) / 128), 256, 0, stream>>>(x, Wk, Kp, D, D, D, D);
    gemm_vt<<<dim3(D / 128, (B * S) / 128), 256, 0, stream>>>(x, Wv, Vt);
    fused_attn<<<dim3(S / 32, B * H), 512, 0, stream>>>(Qp, Kp, Vt, mask, attn, out);
    ln_residual<<<dim3(B * S), 256, 0, stream>>>(x, gamma, beta, out);
  } else {
    // Tier C: validated round-4 pipeline
    ushort_t* Qp = ws;
    ushort_t* Kp = Qp + BSD;
    ushort_t* Vt = Qp;
    gemm_proj<<<dim3(D / 128, (B * S) / 128), 256, 0, stream>>>(x, Wq, Qp, D, D, D, D);
    gemm_proj<<<dim3(D / 128, (B * S) / 128), 256, 0, stream>>>(x, Wk, Kp, D, D, D, D);
    attn_scores<<<dim3(S / 16, B * H), 256, 0, stream>>>(Qp, Kp, mask, attn);
    gemm_vt<<<dim3(D / 128, (B * S) / 128), 256, 0, stream>>>(x, Wv, Vt);
    gemm_pv<<<dim3(1, S / 128, B * H), 256, 0, stream>>>(attn, Vt, out);
    ln_residual<<<dim3(B * S), 256, 0, stream>>>(x, gamma, beta, out);
  }
}